// Round 6
// baseline (734.285 us; speedup 1.0000x reference)
//
#include <hip/hip_runtime.h>

// ============================================================================
// SEB_59201829208446 round 9:
//   - conv_k v5: T14 async-STAGE x-prefetch — gather step k+1's x into regs
//     right after the 2nd barrier (in flight under MFMA + barrier + A-stage),
//     double-step loop with named va/vb2 buffers (rule #20: static indexing).
//     Geometry unchanged from r8 (M=256, N64, Ksplit2, 832 blk, 40 KB LDS).
//   - NS chain fuse/pair -> fuseN64_k: 128x64 tiles, 48 KB LDS, 512 thr,
//     grid (4,2,64)=512 blocks = 2 blocks/CU resident (was 64 KB, 1/CU, 25%).
//     gemm2_pair_k retired (= fuseN64_k<0> with plain params).
//   - BN stats/apply vectorized float4 (784 = 196 quads exactly).
// 24 launches. Round 8 was 681 us (conv 122, occupancy-starved NS chain).
// ============================================================================

typedef unsigned short u16;
typedef __attribute__((ext_vector_type(8))) short bf16x8;
typedef __attribute__((ext_vector_type(4))) float f32x4;

__device__ __forceinline__ u16 f2bf(float f) {
  unsigned u = __builtin_bit_cast(unsigned, f);
  u += 0x7FFFu + ((u >> 16) & 1u);
  return (u16)(u >> 16);
}
__device__ __forceinline__ float bf2f(u16 h) {
  unsigned u = ((unsigned)h) << 16;
  return __builtin_bit_cast(float, u);
}

// ---------------------------------------------------------------------------
// fuseN64_k: dual-task 128x64-tile split GEMM, 512 thr (8 waves, 4m x 2n),
// grid (4,2,64): z<32 -> task0, z>=32 -> task1. 48 KB LDS -> 2 blocks/CU.
// MODE0 epilogue: C = al*(A@B) + b1*cf + dg*I (split out)
// MODE1 (task1 only): C = A@B raw; D = C*hc1 + cf*hc2 + hc3*I
// B assumed symmetric (reads B rows as columns).
// ---------------------------------------------------------------------------
template<int MB>
__global__ __launch_bounds__(512)
void fuseN64_k(const u16* __restrict__ A0, const u16* __restrict__ B0, u16* __restrict__ C0,
               float al0, float b10, float dg0, const float* __restrict__ cf0,
               const u16* __restrict__ A1, const u16* __restrict__ B1, u16* __restrict__ C1,
               u16* __restrict__ D1, float al1, float b11, float dg1,
               float hc1, float hc2, float hc3, const float* __restrict__ cf1, long LO)
{
  __shared__ u16 ldsA[2][128][8][8];   // 32 KB
  __shared__ u16 ldsB[2][64][8][8];    // 16 KB
  int z = blockIdx.z;
  const bool hB = (z >= 32);
  const u16 *Ah, *Bh; u16 *C, *D = nullptr;
  float al, b1, dg; const float* cf;
  if (!hB) { Ah = A0; Bh = B0; C = C0; al = al0; b1 = b10; dg = dg0; cf = cf0; }
  else { z -= 32; Ah = A1; Bh = B1; C = C1; D = D1; al = al1; b1 = b11; dg = dg1; cf = cf1; }
  const long boff = (long)z * 65536;
  const int row0 = blockIdx.y * 128, col0 = blockIdx.x * 64;
  const int tid = threadIdx.x;
  const int wave = tid >> 6, lane = tid & 63;
  const int wm = wave >> 1, wn = wave & 1;    // 4m x 2n
  const int mL = lane & 15, q = lane >> 4;
  const u16* baseA[2] = {Ah + boff, Ah + LO + boff};
  const u16* baseB[2] = {Bh + boff, Bh + LO + boff};

  f32x4 acc[2][2];
#pragma unroll
  for (int i = 0; i < 2; ++i)
#pragma unroll
    for (int j = 0; j < 2; ++j) acc[i][j] = {0.f, 0.f, 0.f, 0.f};

  for (int k0 = 0; k0 < 256; k0 += 64) {
    __syncthreads();
#pragma unroll
    for (int it = 0; it < 4; ++it) {           // A: 2 planes x 2 its
      const int t = it >> 1;
      const int r = ((it & 1) << 9) + tid;
      const int m = r >> 3, c = r & 7;
      *reinterpret_cast<uint4*>(&ldsA[t][m][c ^ (m & 7)][0]) =
          *reinterpret_cast<const uint4*>(baseA[t] + (long)(row0 + m) * 256 + k0 + c * 8);
    }
#pragma unroll
    for (int it = 0; it < 2; ++it) {           // B: 2 planes x 1 it
      const int m = tid >> 3, c = tid & 7;
      *reinterpret_cast<uint4*>(&ldsB[it][m][c ^ (m & 7)][0]) =
          *reinterpret_cast<const uint4*>(baseB[it] + (long)(col0 + m) * 256 + k0 + c * 8);
    }
    __syncthreads();
#pragma unroll
    for (int kk = 0; kk < 2; ++kk) {
      bf16x8 ah[2], alo[2], bh[2], bl[2];
#pragma unroll
      for (int i = 0; i < 2; ++i) {
        const int ma = wm * 32 + i * 16 + mL;
        const int ca = (kk * 4 + q) ^ (ma & 7);
        ah[i]  = *reinterpret_cast<const bf16x8*>(&ldsA[0][ma][ca][0]);
        alo[i] = *reinterpret_cast<const bf16x8*>(&ldsA[1][ma][ca][0]);
      }
#pragma unroll
      for (int j = 0; j < 2; ++j) {
        const int nb = wn * 32 + j * 16 + mL;
        const int cb = (kk * 4 + q) ^ (nb & 7);
        bh[j] = *reinterpret_cast<const bf16x8*>(&ldsB[0][nb][cb][0]);
        bl[j] = *reinterpret_cast<const bf16x8*>(&ldsB[1][nb][cb][0]);
      }
#pragma unroll
      for (int i = 0; i < 2; ++i)
#pragma unroll
        for (int j = 0; j < 2; ++j) {
          acc[i][j] = __builtin_amdgcn_mfma_f32_16x16x32_bf16(ah[i],  bh[j], acc[i][j], 0, 0, 0);
          acc[i][j] = __builtin_amdgcn_mfma_f32_16x16x32_bf16(ah[i],  bl[j], acc[i][j], 0, 0, 0);
          acc[i][j] = __builtin_amdgcn_mfma_f32_16x16x32_bf16(alo[i], bh[j], acc[i][j], 0, 0, 0);
        }
    }
  }

#pragma unroll
  for (int i = 0; i < 2; ++i) {
    const int rbase = row0 + wm * 32 + i * 16 + q * 4;
#pragma unroll
    for (int j = 0; j < 2; ++j) {
      const int cc = col0 + wn * 32 + j * 16 + mL;
#pragma unroll
      for (int rg = 0; rg < 4; ++rg) {
        const int rr = rbase + rg;
        const long o = boff + (long)rr * 256 + cc;
        const float vr = acc[i][j][rg];
        if (MB == 1 && hB) {
          u16 h = f2bf(vr);
          C[o] = h; C[o + LO] = f2bf(vr - bf2f(h));
          float hv = fmaf(vr, hc1, cf[o] * hc2);
          if (rr == cc) hv += hc3;
          h = f2bf(hv);
          D[o] = h; D[o + LO] = f2bf(hv - bf2f(h));
        } else {
          float v = al * vr;
          if (cf) v = fmaf(b1, cf[o], v);
          if (rr == cc) v += dg;
          const u16 h = f2bf(v);
          C[o] = h; C[o + LO] = f2bf(v - bf2f(h));
        }
      }
    }
  }
}

// ---------------------------------------------------------------------------
// Single-task 128x64-tile split GEMM, 512 thr, grid (4,2,32).
// MODE 0: C = alpha*(A@B) + b1*cf + diag*I; MODE 2: Frobenius atomic only.
// ---------------------------------------------------------------------------
template<int MODE>
__global__ __launch_bounds__(512)
void gemmN64_k(const u16* __restrict__ Ah, const u16* __restrict__ Al,
               const u16* __restrict__ Bh, const u16* __restrict__ Bl,
               u16* __restrict__ Ch, u16* __restrict__ Cl,
               const float* __restrict__ cf, float alpha, float b1, float diag,
               float* __restrict__ attn2)
{
  __shared__ u16 ldsA[2][128][8][8];
  __shared__ u16 ldsB[2][64][8][8];
  const long boff = (long)blockIdx.z * 65536;
  const int row0 = blockIdx.y * 128, col0 = blockIdx.x * 64;
  const int tid = threadIdx.x;
  const int wave = tid >> 6, lane = tid & 63;
  const int wm = wave >> 1, wn = wave & 1;    // 4m x 2n
  const int mL = lane & 15, q = lane >> 4;
  const u16* baseA[2] = {Ah + boff, Al + boff};
  const u16* baseB[2] = {Bh + boff, Bl + boff};

  f32x4 acc[2][2];
#pragma unroll
  for (int i = 0; i < 2; ++i)
#pragma unroll
    for (int j = 0; j < 2; ++j) acc[i][j] = {0.f, 0.f, 0.f, 0.f};

  for (int k0 = 0; k0 < 256; k0 += 64) {
    __syncthreads();
#pragma unroll
    for (int it = 0; it < 4; ++it) {
      const int t = it >> 1;
      const int r = ((it & 1) << 9) + tid;
      const int m = r >> 3, c = r & 7;
      *reinterpret_cast<uint4*>(&ldsA[t][m][c ^ (m & 7)][0]) =
          *reinterpret_cast<const uint4*>(baseA[t] + (long)(row0 + m) * 256 + k0 + c * 8);
    }
#pragma unroll
    for (int it = 0; it < 2; ++it) {
      const int m = tid >> 3, c = tid & 7;
      *reinterpret_cast<uint4*>(&ldsB[it][m][c ^ (m & 7)][0]) =
          *reinterpret_cast<const uint4*>(baseB[it] + (long)(col0 + m) * 256 + k0 + c * 8);
    }
    __syncthreads();
#pragma unroll
    for (int kk = 0; kk < 2; ++kk) {
      bf16x8 ah[2], alo[2], bh[2], bl[2];
#pragma unroll
      for (int i = 0; i < 2; ++i) {
        const int ma = wm * 32 + i * 16 + mL;
        const int ca = (kk * 4 + q) ^ (ma & 7);
        ah[i]  = *reinterpret_cast<const bf16x8*>(&ldsA[0][ma][ca][0]);
        alo[i] = *reinterpret_cast<const bf16x8*>(&ldsA[1][ma][ca][0]);
      }
#pragma unroll
      for (int j = 0; j < 2; ++j) {
        const int nb = wn * 32 + j * 16 + mL;
        const int cb = (kk * 4 + q) ^ (nb & 7);
        bh[j] = *reinterpret_cast<const bf16x8*>(&ldsB[0][nb][cb][0]);
        bl[j] = *reinterpret_cast<const bf16x8*>(&ldsB[1][nb][cb][0]);
      }
#pragma unroll
      for (int i = 0; i < 2; ++i)
#pragma unroll
        for (int j = 0; j < 2; ++j) {
          acc[i][j] = __builtin_amdgcn_mfma_f32_16x16x32_bf16(ah[i],  bh[j], acc[i][j], 0, 0, 0);
          acc[i][j] = __builtin_amdgcn_mfma_f32_16x16x32_bf16(ah[i],  bl[j], acc[i][j], 0, 0, 0);
          acc[i][j] = __builtin_amdgcn_mfma_f32_16x16x32_bf16(alo[i], bh[j], acc[i][j], 0, 0, 0);
        }
    }
  }

  if (MODE == 2) {
    float ssum = 0.f;
#pragma unroll
    for (int i = 0; i < 2; ++i)
#pragma unroll
      for (int j = 0; j < 2; ++j)
#pragma unroll
        for (int rg = 0; rg < 4; ++rg) ssum = fmaf(acc[i][j][rg], acc[i][j][rg], ssum);
#pragma unroll
    for (int o = 32; o > 0; o >>= 1) ssum += __shfl_down(ssum, o);
    __syncthreads();
    float* red = (float*)&ldsA[0][0][0][0];
    if (lane == 0) red[wave] = ssum;
    __syncthreads();
    if (tid == 0) {
      float t8 = 0.f;
#pragma unroll
      for (int wv = 0; wv < 8; ++wv) t8 += red[wv];
      atomicAdd(attn2 + blockIdx.z, t8);
    }
    return;
  }

#pragma unroll
  for (int i = 0; i < 2; ++i) {
    const int rbase = row0 + wm * 32 + i * 16 + q * 4;
#pragma unroll
    for (int j = 0; j < 2; ++j) {
      const int cc = col0 + wn * 32 + j * 16 + mL;
#pragma unroll
      for (int rg = 0; rg < 4; ++rg) {
        const int rr = rbase + rg;
        const long o = boff + (long)rr * 256 + cc;
        float v = alpha * acc[i][j][rg];
        if (cf) v = fmaf(b1, cf[o], v);
        if (rr == cc) v += diag;
        const u16 h = f2bf(v);
        Ch[o] = h; Cl[o] = f2bf(v - bf2f(h));
      }
    }
  }
}

// ---------------------------------------------------------------------------
// conv1x1 v5: z[b] = W(256x2048) @ x_b(2048x784). M=256, N-tile 64, K-split 2,
// 512 thr, grid (13,2,32)=832 blocks, 40 KB LDS. T14 x-prefetch: gather step
// k+1 into regs after the 2nd barrier so latency hides under MFMA+A-stage.
// ---------------------------------------------------------------------------
__global__ __launch_bounds__(512)
void conv_k(const u16* __restrict__ wb, const float* __restrict__ x,
            float* __restrict__ z0, float* __restrict__ z1)
{
  __shared__ u16 ldsA[256][8][8];   // 32 KB: all 256 W rows
  __shared__ u16 ldsB[64][8][8];    // 8 KB
  const int tid = threadIdx.x;
  const int b = blockIdx.z;
  const int n0 = blockIdx.x * 64;
  const int kb0 = blockIdx.y * 1024;
  const int wave = tid >> 6, lane = tid & 63;
  const int wm = wave >> 1, wn = wave & 1;    // 4m x 2n
  const int mL = lane & 15, q = lane >> 4;
  const float* xb = x + (long)b * 2048 * 784;
  float* zp = (blockIdx.y == 0 ? z0 : z1);

  f32x4 acc[4][2];
#pragma unroll
  for (int i = 0; i < 4; ++i)
#pragma unroll
    for (int j = 0; j < 2; ++j) acc[i][j] = {0.f, 0.f, 0.f, 0.f};

  const int kc = tid >> 6, nc = tid & 63;     // kc = k-octet (== wave), nc = n
  const int gn = n0 + nc;
  const bool nok = (gn < 784);
  const int ch = kc ^ (nc & 7);

  auto GATHER = [&](int kg, float* v) {
    const float* ps = xb + (long)(kg + kc * 8) * 784 + gn;
#pragma unroll
    for (int jk = 0; jk < 8; ++jk) v[jk] = nok ? ps[(long)jk * 784] : 0.f;
  };
  auto STAGEA = [&](int kg) {
#pragma unroll
    for (int it = 0; it < 4; ++it) {
      const int g = it * 512 + tid;
      const int m = g >> 3, c = g & 7;
      *reinterpret_cast<uint4*>(&ldsA[m][c ^ (m & 7)][0]) =
          *reinterpret_cast<const uint4*>(wb + (long)m * 2048 + kg + c * 8);
    }
  };
  auto WRITEB = [&](const float* v) {
    ushort4 ua, ub;
    ua.x = f2bf(v[0]); ua.y = f2bf(v[1]); ua.z = f2bf(v[2]); ua.w = f2bf(v[3]);
    ub.x = f2bf(v[4]); ub.y = f2bf(v[5]); ub.z = f2bf(v[6]); ub.w = f2bf(v[7]);
    *reinterpret_cast<ushort4*>(&ldsB[nc][ch][0]) = ua;
    *reinterpret_cast<ushort4*>(&ldsB[nc][ch][4]) = ub;
  };
  auto DOMFMA = [&]() {
#pragma unroll
    for (int kk = 0; kk < 2; ++kk) {
      bf16x8 af[4], bfv[2];
#pragma unroll
      for (int i = 0; i < 4; ++i) {
        const int ma = wm * 64 + i * 16 + mL;
        af[i] = *reinterpret_cast<const bf16x8*>(&ldsA[ma][(kk * 4 + q) ^ (ma & 7)][0]);
      }
#pragma unroll
      for (int j = 0; j < 2; ++j) {
        const int nb = wn * 32 + j * 16 + mL;
        bfv[j] = *reinterpret_cast<const bf16x8*>(&ldsB[nb][(kk * 4 + q) ^ (nb & 7)][0]);
      }
#pragma unroll
      for (int i = 0; i < 4; ++i)
#pragma unroll
        for (int j = 0; j < 2; ++j)
          acc[i][j] = __builtin_amdgcn_mfma_f32_16x16x32_bf16(af[i], bfv[j], acc[i][j], 0, 0, 0);
    }
  };

  float va[8], vb2[8];
  GATHER(kb0, va);
  for (int k0 = 0; k0 < 1024; k0 += 128) {
    __syncthreads();
    STAGEA(kb0 + k0);
    WRITEB(va);
    __syncthreads();
    GATHER(kb0 + k0 + 64, vb2);      // in flight under MFMA + barrier + stage
    DOMFMA();
    __syncthreads();
    STAGEA(kb0 + k0 + 64);
    WRITEB(vb2);
    __syncthreads();
    if (k0 + 128 < 1024) GATHER(kb0 + k0 + 128, va);
    DOMFMA();
  }

#pragma unroll
  for (int i = 0; i < 4; ++i) {
    const int rbase = wm * 64 + i * 16 + q * 4;
#pragma unroll
    for (int j = 0; j < 2; ++j) {
      const int cc = n0 + wn * 32 + j * 16 + mL;
      if (cc >= 784) continue;
#pragma unroll
      for (int rg = 0; rg < 4; ++rg)
        zp[((long)b * 256 + rbase + rg) * 784 + cc] = acc[i][j][rg];
    }
  }
}

// ---------------------------------------------------------------------------
// Gram (512 thr): cov[b] = (1/784) zb@zb^T - mu mu^T; C2 = split(cov).
// Tile 128x64, grid (4,2,32)=256 blocks. K=832 (13 rounds).
// ---------------------------------------------------------------------------
__global__ __launch_bounds__(512)
void gram_k(const u16* __restrict__ zb, const float* __restrict__ rs,
            float* __restrict__ cov, u16* __restrict__ C2h, u16* __restrict__ C2l)
{
  __shared__ u16 ldsA[128][8][8];   // 16 KB
  __shared__ u16 ldsB[64][8][8];    // 8 KB
  const int tid = threadIdx.x;
  const int b = blockIdx.z;
  const int col0 = blockIdx.x * 64, row0 = blockIdx.y * 128;
  const int wave = tid >> 6, lane = tid & 63;
  const int wm = wave >> 1, wn = wave & 1;    // 4m x 2n
  const int mL = lane & 15, q = lane >> 4;
  const u16* zbb = zb + (long)b * 256 * 832;

  f32x4 acc[2][2];
#pragma unroll
  for (int i = 0; i < 2; ++i)
#pragma unroll
    for (int j = 0; j < 2; ++j) acc[i][j] = {0.f, 0.f, 0.f, 0.f};

  for (int k0 = 0; k0 < 832; k0 += 64) {
    __syncthreads();
#pragma unroll
    for (int it = 0; it < 2; ++it) {
      const int r = it * 512 + tid;
      const int m = r >> 3, c = r & 7;
      *reinterpret_cast<uint4*>(&ldsA[m][c ^ (m & 7)][0]) =
          *reinterpret_cast<const uint4*>(zbb + (long)(row0 + m) * 832 + k0 + c * 8);
    }
    {
      const int m = tid >> 3, c = tid & 7;
      *reinterpret_cast<uint4*>(&ldsB[m][c ^ (m & 7)][0]) =
          *reinterpret_cast<const uint4*>(zbb + (long)(col0 + m) * 832 + k0 + c * 8);
    }
    __syncthreads();
#pragma unroll
    for (int kk = 0; kk < 2; ++kk) {
      bf16x8 af[2], bfv[2];
#pragma unroll
      for (int i = 0; i < 2; ++i) {
        const int ma = wm * 32 + i * 16 + mL;
        af[i] = *reinterpret_cast<const bf16x8*>(&ldsA[ma][(kk * 4 + q) ^ (ma & 7)][0]);
      }
#pragma unroll
      for (int j = 0; j < 2; ++j) {
        const int nb = wn * 32 + j * 16 + mL;
        bfv[j] = *reinterpret_cast<const bf16x8*>(&ldsB[nb][(kk * 4 + q) ^ (nb & 7)][0]);
      }
#pragma unroll
      for (int i = 0; i < 2; ++i)
#pragma unroll
        for (int j = 0; j < 2; ++j)
          acc[i][j] = __builtin_amdgcn_mfma_f32_16x16x32_bf16(af[i], bfv[j], acc[i][j], 0, 0, 0);
    }
  }
  const float inv_m = 1.f / 784.f;
#pragma unroll
  for (int i = 0; i < 2; ++i) {
    const int rr0 = row0 + wm * 32 + i * 16 + q * 4;
#pragma unroll
    for (int j = 0; j < 2; ++j) {
      const int cc = col0 + wn * 32 + j * 16 + mL;
      const float mu_c = rs[b * 256 + cc] * inv_m;
#pragma unroll
      for (int rg = 0; rg < 4; ++rg) {
        const int rr = rr0 + rg;
        const float mu_r = rs[b * 256 + rr] * inv_m;
        const long o = ((long)b * 256 + rr) * 256 + cc;
        const float cv = fmaf(acc[i][j][rg], inv_m, -mu_r * mu_c);
        cov[o] = cv;
        const u16 h = f2bf(cv);
        C2h[o] = h; C2l[o] = f2bf(cv - bf2f(h));
      }
    }
  }
}

// ---- BN pass 1 (float4): partial sums/sumsq per (channel, slice of 4) -----
__global__ __launch_bounds__(256)
void bn_stats_k(const float* __restrict__ z0, const float* __restrict__ z1,
                float* __restrict__ ps, float* __restrict__ pq)
{
  const int d = blockIdx.x, sl = blockIdx.y, t = threadIdx.x;
  const int lane = t & 63, wid = t >> 6;
  __shared__ float ws[4], wq[4];
  float s = 0.f, qq = 0.f;
  for (int b = sl * 4; b < sl * 4 + 4; ++b) {
    const long off = ((long)b * 256 + d) * 784;
    for (int q4 = t; q4 < 196; q4 += 256) {
      const float4 a = *reinterpret_cast<const float4*>(z0 + off + q4 * 4);
      const float4 c = *reinterpret_cast<const float4*>(z1 + off + q4 * 4);
      const float v0 = a.x + c.x, v1 = a.y + c.y, v2 = a.z + c.z, v3 = a.w + c.w;
      s += v0 + v1 + v2 + v3;
      qq = fmaf(v0, v0, fmaf(v1, v1, fmaf(v2, v2, fmaf(v3, v3, qq))));
    }
  }
#pragma unroll
  for (int o = 32; o > 0; o >>= 1) { s += __shfl_down(s, o); qq += __shfl_down(qq, o); }
  if (lane == 0) { ws[wid] = s; wq[wid] = qq; }
  __syncthreads();
  if (t == 0) {
    ps[d * 8 + sl] = ws[0] + ws[1] + ws[2] + ws[3];
    pq[d * 8 + sl] = wq[0] + wq[1] + wq[2] + wq[3];
  }
}

// ---- BN pass 2 (float4): finalize, normalize+ReLU+cast, rowsums -----------
__global__ __launch_bounds__(256)
void bn_apply_k(const float* __restrict__ z0, const float* __restrict__ z1,
                const float* __restrict__ gamma, const float* __restrict__ beta,
                const float* __restrict__ ps, const float* __restrict__ pq,
                u16* __restrict__ zb, float* __restrict__ rs)
{
  const int d = blockIdx.x, b = blockIdx.y, t = threadIdx.x;
  const int lane = t & 63, wid = t >> 6;
  __shared__ float bc[2], ws[4];
  if (t == 0) {
    float sum = 0.f, sq = 0.f;
#pragma unroll
    for (int s8 = 0; s8 < 8; ++s8) { sum += ps[d * 8 + s8]; sq += pq[d * 8 + s8]; }
    const float inv_n = 1.f / 25088.f;
    const float mean = sum * inv_n;
    const float var = sq * inv_n - mean * mean;
    const float sc = gamma[d] * rsqrtf(var + 1e-5f);
    bc[0] = sc; bc[1] = fmaf(-mean, sc, beta[d]);
  }
  __syncthreads();
  const float sc = bc[0], sh = bc[1];
  const long off = ((long)b * 256 + d) * 784;
  u16* qp = zb + ((long)b * 256 + d) * 832;
  float rsum = 0.f;
  for (int q4 = t; q4 < 208; q4 += 256) {
    ushort4 u = {0, 0, 0, 0};
    if (q4 < 196) {
      const float4 a = *reinterpret_cast<const float4*>(z0 + off + q4 * 4);
      const float4 c = *reinterpret_cast<const float4*>(z1 + off + q4 * 4);
      const float v0 = fmaxf(fmaf(a.x + c.x, sc, sh), 0.f);
      const float v1 = fmaxf(fmaf(a.y + c.y, sc, sh), 0.f);
      const float v2 = fmaxf(fmaf(a.z + c.z, sc, sh), 0.f);
      const float v3 = fmaxf(fmaf(a.w + c.w, sc, sh), 0.f);
      u.x = f2bf(v0); u.y = f2bf(v1); u.z = f2bf(v2); u.w = f2bf(v3);
      rsum += v0 + v1 + v2 + v3;
    }
    *reinterpret_cast<ushort4*>(qp + q4 * 4) = u;
  }
#pragma unroll
  for (int o = 32; o > 0; o >>= 1) rsum += __shfl_down(rsum, o);
  if (lane == 0) ws[wid] = rsum;
  __syncthreads();
  if (t == 0) rs[b * 256 + d] = ws[0] + ws[1] + ws[2] + ws[3];
}

// ---- power iteration: j-dim split x4 across 1024 threads ------------------
__global__ __launch_bounds__(1024)
void power_k(const float* __restrict__ cov, float* __restrict__ s,
             float* __restrict__ attn2)
{
  const int b = blockIdx.x, tid = threadIdx.x;
  const int i = tid & 255, g = tid >> 8;        // g in 0..3
  const float* A = cov + (long)b * 65536;
  __shared__ float v[256];
  __shared__ float part[4][256];
  __shared__ float red[4];
  if (g == 0) v[i] = 1.f;
  __syncthreads();
  float lam = 1.f;
  for (int it = 0; it < 10; ++it) {
    float u = 0.f;
    const int jb = g * 64;
#pragma unroll 8
    for (int j = jb; j < jb + 64; ++j) u = fmaf(A[(long)j * 256 + i], v[j], u);
    part[g][i] = u;
    __syncthreads();
    if (g == 0) {
      u = part[0][i] + part[1][i] + part[2][i] + part[3][i];
      float ss = u * u;
#pragma unroll
      for (int o = 32; o > 0; o >>= 1) ss += __shfl_down(ss, o);
      if ((i & 63) == 0) red[i >> 6] = ss;
    }
    __syncthreads();
    lam = sqrtf(red[0] + red[1] + red[2] + red[3]);
    if (g == 0) v[i] = u / lam;
    __syncthreads();
  }
  if (tid == 0) { s[b] = 1.8f / lam; attn2[b] = 0.f; }
}

// ---- init: Y0 = split(s*cov); T0 = split(1.5I - 0.5*s*cov)  (Z0 = I) ------
__global__ __launch_bounds__(256)
void init_k(const float* __restrict__ cov, const float* __restrict__ s,
            u16* __restrict__ Yh, u16* __restrict__ Yl,
            u16* __restrict__ Th, u16* __restrict__ Tl)
{
  const int b = blockIdx.y, i = blockIdx.x, j = threadIdx.x;
  const long o = ((long)b * 256 + i) * 256 + j;
  const float a = cov[o] * s[b];
  u16 h = f2bf(a);
  Yh[o] = h; Yl[o] = f2bf(a - bf2f(h));
  float tv = -0.5f * a;
  if (i == j) tv += 1.5f;
  h = f2bf(tv);
  Th[o] = h; Tl[o] = f2bf(tv - bf2f(h));
}

// ---- epilogue: y = (Y/sqrt(s)) * (1 + ||S2||_F/sqrt(s)), triu extract -----
__global__ __launch_bounds__(256)
void out_k(const u16* __restrict__ Yh, const u16* __restrict__ Yl,
           const float* __restrict__ s, const float* __restrict__ attn2,
           float* __restrict__ out)
{
  const int i = blockIdx.x, b = blockIdx.y, j = threadIdx.x;
  if (j < i) return;
  const float inv = rsqrtf(s[b]);
  const float nrm = fmaxf(sqrtf(fmaxf(attn2[b], 0.f)) * inv, 1e-12f);
  const float scv = inv * (1.f + nrm);
  const long o = ((long)b * 256 + i) * 256 + j;
  const long off = (long)b * 32896 + (long)i * 256 - (long)i * (i - 1) / 2 + (j - i);
  out[off] = (bf2f(Yh[o]) + bf2f(Yl[o])) * scv;
}

__global__ __launch_bounds__(256)
void cast_w_k(const float* __restrict__ w, u16* __restrict__ wb)
{
  const int idx = blockIdx.x * 256 + threadIdx.x;
  wb[idx] = f2bf(w[idx]);
}

extern "C" void kernel_launch(void* const* d_in, const int* in_sizes, int n_in,
                              void* d_out, int out_size, void* d_ws, size_t ws_size,
                              hipStream_t stream)
{
  const float* x     = (const float*)d_in[0];   // [32,2048,28,28]
  const float* w     = (const float*)d_in[1];   // [256,2048]
  const float* gamma = (const float*)d_in[2];
  const float* beta  = (const float*)d_in[3];
  float* out = (float*)d_out;

  // ---- workspace: 9 split-pair slots + z0 + z1 + zb + cov + st ------------
  const long PS = 4194304;  // u16 per slot (hi 2,097,152 then lo 2,097,152)
  const long LO = 2097152;
  u16* S[9];
  for (int k = 0; k < 9; ++k) S[k] = (u16*)d_ws + (long)k * PS;
  char* base = (char*)d_ws;
  float* z0  = (float*)(base + 75497472);       // 25,690,112 B
  float* z1  = (float*)(base + 101187584);      // 25,690,112 B
  u16*   zb  = (u16*)(base + 126877696);        // 13,631,488 B
  float* cov = (float*)(base + 140509184);      // 8,388,608 B
  u16*   wbuf = (u16*)(base + 140509184);       // 1 MB, dead before gram
  float* st  = (float*)(base + 148897792);      // ~50 KB of scalars
  float* sv = st, *attn2 = st + 32, *rs = st + 64;
  float* ps = st + 64 + 8192, *pq = ps + 2048;
  u16 *C2 = S[5], *V = S[6], *Ha = S[7], *Hb = S[8];

  const dim3 blk(256), blk5(512);
  const dim3 gF(4, 2, 64);   // fuseN64 launches: 512 blocks x 512 thr (2/CU)
  const dim3 gT(4, 2, 32);   // single-task 128x64: 256 blocks x 512 thr
  const dim3 gE(256, 32);
  const float* nullf = nullptr;

  // 1) conv: W precast, then M256/Ksplit2 GEMM with x-prefetch -> z0/z1
  cast_w_k<<<dim3(2048), blk, 0, stream>>>(w, wbuf);
  conv_k<<<dim3(13, 2, 32), blk5, 0, stream>>>(wbuf, x, z0, z1);
  // 2) BN: stats (2048 blocks) + apply (8192 blocks), float4, z = z0+z1
  bn_stats_k<<<dim3(256, 8), blk, 0, stream>>>(z0, z1, ps, pq);
  bn_apply_k<<<dim3(256, 32), blk, 0, stream>>>(z0, z1, gamma, beta, ps, pq, zb, rs);
  // 3) covariance 128x64 tiles (+ C2 split folded)
  gram_k<<<gT, blk5, 0, stream>>>(zb, rs, cov, C2, C2 + LO);
  // 4) lambda_max; s = 1.8/lam; zero attn2
  power_k<<<dim3(32), dim3(1024), 0, stream>>>(cov, sv, attn2);
  // 5) NS init: Y0 -> S0, T0 -> S1 (Z0 = I => Z1 = T0)
  init_k<<<gE, blk, 0, stream>>>(cov, sv, S[0], S[0] + LO, S[1], S[1] + LO);

  // F1: z<32: Y1 = Y0@T0 -> S2 ; z>=32: V = C2@C2 dual-out Ha = H3
  fuseN64_k<1><<<gF, blk5, 0, stream>>>(
      S[0], S[1], S[2], 1.f, 0.f, 0.f, nullf,
      C2, C2, V, Ha, 1.f, 0.f, 0.f,
      1.f / 40320.f, -1.f / 5040.f, 1.f / 720.f, cov, LO);

  // 6) coupled NS iters 1..7, expm H-chain co-scheduled into iters 1..3.
  int iY = 2, iZ = 1, fa = 0, fb = 3, fc = 4;
  for (int it = 1; it <= 7; ++it) {
    const int iT = fa;
    if (it == 1)        // T1 || Hb = H2 = V@Ha - cov/120 + I/24
      fuseN64_k<0><<<gF, blk5, 0, stream>>>(
          S[iZ], S[iY], S[iT], -0.5f, 0.f, 1.5f, nullf,
          V, Ha, Hb, (u16*)nullptr, 1.f, -1.f / 120.f, 1.f / 24.f,
          0.f, 0.f, 0.f, cov, LO);
    else if (it == 2)   // T2 || Ha = H1 = V@Hb - cov/6 + I/2
      fuseN64_k<0><<<gF, blk5, 0, stream>>>(
          S[iZ], S[iY], S[iT], -0.5f, 0.f, 1.5f, nullf,
          V, Hb, Ha, (u16*)nullptr, 1.f, -1.f / 6.f, 0.5f,
          0.f, 0.f, 0.f, cov, LO);
    else if (it == 3)   // T3 || Hb = H0 = V@Ha - cov + I = e^{-cov}
      fuseN64_k<0><<<gF, blk5, 0, stream>>>(
          S[iZ], S[iY], S[iT], -0.5f, 0.f, 1.5f, nullf,
          V, Ha, Hb, (u16*)nullptr, 1.f, -1.f, 1.f,
          0.f, 0.f, 0.f, cov, LO);
    else                // T4..T7 standalone
      gemmN64_k<0><<<gT, blk5, 0, stream>>>(
          S[iZ], S[iZ] + LO, S[iY], S[iY] + LO, S[iT], S[iT] + LO,
          nullf, -0.5f, 0.f, 1.5f, (float*)nullptr);
    if (it < 7) {       // pair: Y' = Y@T ; Z' = T@Z  (both plain)
      fuseN64_k<0><<<gF, blk5, 0, stream>>>(
          S[iY], S[iT], S[fb], 1.f, 0.f, 0.f, nullf,
          S[iT], S[iZ], S[fc], (u16*)nullptr, 1.f, 0.f, 0.f,
          0.f, 0.f, 0.f, nullf, LO);
      const int nY = fb, nZ = fc;
      fa = iY; fb = iZ; fc = iT;
      iY = nY; iZ = nZ;
    } else {            // last iter: Z not needed
      gemmN64_k<0><<<gT, blk5, 0, stream>>>(
          S[iY], S[iY] + LO, S[iT], S[iT] + LO, S[fb], S[fb] + LO,
          nullf, 1.f, 0.f, 0.f, (float*)nullptr);
      iY = fb;
    }
  }

  // 7) ||Y@E||_F^2 -> attn2 (atomic, no C write); epilogue
  gemmN64_k<2><<<gT, blk5, 0, stream>>>(
      S[iY], S[iY] + LO, Hb, Hb + LO, (u16*)nullptr, (u16*)nullptr,
      nullf, 1.f, 0.f, 0.f, attn2);
  out_k<<<gE, blk, 0, stream>>>(S[iY], S[iY] + LO, sv, attn2, out);
}

// Round 7
// 670.519 us; speedup vs baseline: 1.0951x; 1.0951x over previous
//
#include <hip/hip_runtime.h>

// ============================================================================
// SEB_59201829208446 round 10:
//   - conv_k v6: revert r9 prefetch (regressed 122->192). Keep x-read-once,
//     restore r7's fat-load staging: wave-specialized (waves 0-3 stage A from
//     wb/L2, waves 4-7 gather x as 8 x float4 = 128B/thread in flight -> HBM
//     concurrency). B k-depth 128 (16KB), A in two 64-k halves (32KB), 48KB
//     LDS = 3 blocks/CU. K-split 4 -> grid (13,4,32) = 1664 blocks. z0..z3
//     partials, BN sums 4.
//   - everything else unchanged from round 9 (fuseN64 NS chain kept: it
//     gained ~17us; r9 total 734 = conv regression +70 minus NS gain).
// 24 launches.
// ============================================================================

typedef unsigned short u16;
typedef __attribute__((ext_vector_type(8))) short bf16x8;
typedef __attribute__((ext_vector_type(4))) float f32x4;

__device__ __forceinline__ u16 f2bf(float f) {
  unsigned u = __builtin_bit_cast(unsigned, f);
  u += 0x7FFFu + ((u >> 16) & 1u);
  return (u16)(u >> 16);
}
__device__ __forceinline__ float bf2f(u16 h) {
  unsigned u = ((unsigned)h) << 16;
  return __builtin_bit_cast(float, u);
}

// ---------------------------------------------------------------------------
// fuseN64_k: dual-task 128x64-tile split GEMM, 512 thr (8 waves, 4m x 2n),
// grid (4,2,64): z<32 -> task0, z>=32 -> task1. 48 KB LDS -> 2+ blocks/CU.
// MODE0 epilogue: C = al*(A@B) + b1*cf + dg*I (split out)
// MODE1 (task1 only): C = A@B raw; D = C*hc1 + cf*hc2 + hc3*I
// ---------------------------------------------------------------------------
template<int MB>
__global__ __launch_bounds__(512)
void fuseN64_k(const u16* __restrict__ A0, const u16* __restrict__ B0, u16* __restrict__ C0,
               float al0, float b10, float dg0, const float* __restrict__ cf0,
               const u16* __restrict__ A1, const u16* __restrict__ B1, u16* __restrict__ C1,
               u16* __restrict__ D1, float al1, float b11, float dg1,
               float hc1, float hc2, float hc3, const float* __restrict__ cf1, long LO)
{
  __shared__ u16 ldsA[2][128][8][8];   // 32 KB
  __shared__ u16 ldsB[2][64][8][8];    // 16 KB
  int z = blockIdx.z;
  const bool hB = (z >= 32);
  const u16 *Ah, *Bh; u16 *C, *D = nullptr;
  float al, b1, dg; const float* cf;
  if (!hB) { Ah = A0; Bh = B0; C = C0; al = al0; b1 = b10; dg = dg0; cf = cf0; }
  else { z -= 32; Ah = A1; Bh = B1; C = C1; D = D1; al = al1; b1 = b11; dg = dg1; cf = cf1; }
  const long boff = (long)z * 65536;
  const int row0 = blockIdx.y * 128, col0 = blockIdx.x * 64;
  const int tid = threadIdx.x;
  const int wave = tid >> 6, lane = tid & 63;
  const int wm = wave >> 1, wn = wave & 1;    // 4m x 2n
  const int mL = lane & 15, q = lane >> 4;
  const u16* baseA[2] = {Ah + boff, Ah + LO + boff};
  const u16* baseB[2] = {Bh + boff, Bh + LO + boff};

  f32x4 acc[2][2];
#pragma unroll
  for (int i = 0; i < 2; ++i)
#pragma unroll
    for (int j = 0; j < 2; ++j) acc[i][j] = {0.f, 0.f, 0.f, 0.f};

  for (int k0 = 0; k0 < 256; k0 += 64) {
    __syncthreads();
#pragma unroll
    for (int it = 0; it < 4; ++it) {           // A: 2 planes x 2 its
      const int t = it >> 1;
      const int r = ((it & 1) << 9) + tid;
      const int m = r >> 3, c = r & 7;
      *reinterpret_cast<uint4*>(&ldsA[t][m][c ^ (m & 7)][0]) =
          *reinterpret_cast<const uint4*>(baseA[t] + (long)(row0 + m) * 256 + k0 + c * 8);
    }
#pragma unroll
    for (int it = 0; it < 2; ++it) {           // B: 2 planes x 1 it
      const int m = tid >> 3, c = tid & 7;
      *reinterpret_cast<uint4*>(&ldsB[it][m][c ^ (m & 7)][0]) =
          *reinterpret_cast<const uint4*>(baseB[it] + (long)(col0 + m) * 256 + k0 + c * 8);
    }
    __syncthreads();
#pragma unroll
    for (int kk = 0; kk < 2; ++kk) {
      bf16x8 ah[2], alo[2], bh[2], bl[2];
#pragma unroll
      for (int i = 0; i < 2; ++i) {
        const int ma = wm * 32 + i * 16 + mL;
        const int ca = (kk * 4 + q) ^ (ma & 7);
        ah[i]  = *reinterpret_cast<const bf16x8*>(&ldsA[0][ma][ca][0]);
        alo[i] = *reinterpret_cast<const bf16x8*>(&ldsA[1][ma][ca][0]);
      }
#pragma unroll
      for (int j = 0; j < 2; ++j) {
        const int nb = wn * 32 + j * 16 + mL;
        const int cb = (kk * 4 + q) ^ (nb & 7);
        bh[j] = *reinterpret_cast<const bf16x8*>(&ldsB[0][nb][cb][0]);
        bl[j] = *reinterpret_cast<const bf16x8*>(&ldsB[1][nb][cb][0]);
      }
#pragma unroll
      for (int i = 0; i < 2; ++i)
#pragma unroll
        for (int j = 0; j < 2; ++j) {
          acc[i][j] = __builtin_amdgcn_mfma_f32_16x16x32_bf16(ah[i],  bh[j], acc[i][j], 0, 0, 0);
          acc[i][j] = __builtin_amdgcn_mfma_f32_16x16x32_bf16(ah[i],  bl[j], acc[i][j], 0, 0, 0);
          acc[i][j] = __builtin_amdgcn_mfma_f32_16x16x32_bf16(alo[i], bh[j], acc[i][j], 0, 0, 0);
        }
    }
  }

#pragma unroll
  for (int i = 0; i < 2; ++i) {
    const int rbase = row0 + wm * 32 + i * 16 + q * 4;
#pragma unroll
    for (int j = 0; j < 2; ++j) {
      const int cc = col0 + wn * 32 + j * 16 + mL;
#pragma unroll
      for (int rg = 0; rg < 4; ++rg) {
        const int rr = rbase + rg;
        const long o = boff + (long)rr * 256 + cc;
        const float vr = acc[i][j][rg];
        if (MB == 1 && hB) {
          u16 h = f2bf(vr);
          C[o] = h; C[o + LO] = f2bf(vr - bf2f(h));
          float hv = fmaf(vr, hc1, cf[o] * hc2);
          if (rr == cc) hv += hc3;
          h = f2bf(hv);
          D[o] = h; D[o + LO] = f2bf(hv - bf2f(h));
        } else {
          float v = al * vr;
          if (cf) v = fmaf(b1, cf[o], v);
          if (rr == cc) v += dg;
          const u16 h = f2bf(v);
          C[o] = h; C[o + LO] = f2bf(v - bf2f(h));
        }
      }
    }
  }
}

// ---------------------------------------------------------------------------
// Single-task 128x64-tile split GEMM, 512 thr, grid (4,2,32).
// MODE 0: C = alpha*(A@B) + b1*cf + diag*I; MODE 2: Frobenius atomic only.
// ---------------------------------------------------------------------------
template<int MODE>
__global__ __launch_bounds__(512)
void gemmN64_k(const u16* __restrict__ Ah, const u16* __restrict__ Al,
               const u16* __restrict__ Bh, const u16* __restrict__ Bl,
               u16* __restrict__ Ch, u16* __restrict__ Cl,
               const float* __restrict__ cf, float alpha, float b1, float diag,
               float* __restrict__ attn2)
{
  __shared__ u16 ldsA[2][128][8][8];
  __shared__ u16 ldsB[2][64][8][8];
  const long boff = (long)blockIdx.z * 65536;
  const int row0 = blockIdx.y * 128, col0 = blockIdx.x * 64;
  const int tid = threadIdx.x;
  const int wave = tid >> 6, lane = tid & 63;
  const int wm = wave >> 1, wn = wave & 1;    // 4m x 2n
  const int mL = lane & 15, q = lane >> 4;
  const u16* baseA[2] = {Ah + boff, Al + boff};
  const u16* baseB[2] = {Bh + boff, Bl + boff};

  f32x4 acc[2][2];
#pragma unroll
  for (int i = 0; i < 2; ++i)
#pragma unroll
    for (int j = 0; j < 2; ++j) acc[i][j] = {0.f, 0.f, 0.f, 0.f};

  for (int k0 = 0; k0 < 256; k0 += 64) {
    __syncthreads();
#pragma unroll
    for (int it = 0; it < 4; ++it) {
      const int t = it >> 1;
      const int r = ((it & 1) << 9) + tid;
      const int m = r >> 3, c = r & 7;
      *reinterpret_cast<uint4*>(&ldsA[t][m][c ^ (m & 7)][0]) =
          *reinterpret_cast<const uint4*>(baseA[t] + (long)(row0 + m) * 256 + k0 + c * 8);
    }
#pragma unroll
    for (int it = 0; it < 2; ++it) {
      const int m = tid >> 3, c = tid & 7;
      *reinterpret_cast<uint4*>(&ldsB[it][m][c ^ (m & 7)][0]) =
          *reinterpret_cast<const uint4*>(baseB[it] + (long)(col0 + m) * 256 + k0 + c * 8);
    }
    __syncthreads();
#pragma unroll
    for (int kk = 0; kk < 2; ++kk) {
      bf16x8 ah[2], alo[2], bh[2], bl[2];
#pragma unroll
      for (int i = 0; i < 2; ++i) {
        const int ma = wm * 32 + i * 16 + mL;
        const int ca = (kk * 4 + q) ^ (ma & 7);
        ah[i]  = *reinterpret_cast<const bf16x8*>(&ldsA[0][ma][ca][0]);
        alo[i] = *reinterpret_cast<const bf16x8*>(&ldsA[1][ma][ca][0]);
      }
#pragma unroll
      for (int j = 0; j < 2; ++j) {
        const int nb = wn * 32 + j * 16 + mL;
        const int cb = (kk * 4 + q) ^ (nb & 7);
        bh[j] = *reinterpret_cast<const bf16x8*>(&ldsB[0][nb][cb][0]);
        bl[j] = *reinterpret_cast<const bf16x8*>(&ldsB[1][nb][cb][0]);
      }
#pragma unroll
      for (int i = 0; i < 2; ++i)
#pragma unroll
        for (int j = 0; j < 2; ++j) {
          acc[i][j] = __builtin_amdgcn_mfma_f32_16x16x32_bf16(ah[i],  bh[j], acc[i][j], 0, 0, 0);
          acc[i][j] = __builtin_amdgcn_mfma_f32_16x16x32_bf16(ah[i],  bl[j], acc[i][j], 0, 0, 0);
          acc[i][j] = __builtin_amdgcn_mfma_f32_16x16x32_bf16(alo[i], bh[j], acc[i][j], 0, 0, 0);
        }
    }
  }

  if (MODE == 2) {
    float ssum = 0.f;
#pragma unroll
    for (int i = 0; i < 2; ++i)
#pragma unroll
      for (int j = 0; j < 2; ++j)
#pragma unroll
        for (int rg = 0; rg < 4; ++rg) ssum = fmaf(acc[i][j][rg], acc[i][j][rg], ssum);
#pragma unroll
    for (int o = 32; o > 0; o >>= 1) ssum += __shfl_down(ssum, o);
    __syncthreads();
    float* red = (float*)&ldsA[0][0][0][0];
    if (lane == 0) red[wave] = ssum;
    __syncthreads();
    if (tid == 0) {
      float t8 = 0.f;
#pragma unroll
      for (int wv = 0; wv < 8; ++wv) t8 += red[wv];
      atomicAdd(attn2 + blockIdx.z, t8);
    }
    return;
  }

#pragma unroll
  for (int i = 0; i < 2; ++i) {
    const int rbase = row0 + wm * 32 + i * 16 + q * 4;
#pragma unroll
    for (int j = 0; j < 2; ++j) {
      const int cc = col0 + wn * 32 + j * 16 + mL;
#pragma unroll
      for (int rg = 0; rg < 4; ++rg) {
        const int rr = rbase + rg;
        const long o = boff + (long)rr * 256 + cc;
        float v = alpha * acc[i][j][rg];
        if (cf) v = fmaf(b1, cf[o], v);
        if (rr == cc) v += diag;
        const u16 h = f2bf(v);
        Ch[o] = h; Cl[o] = f2bf(v - bf2f(h));
      }
    }
  }
}

// ---------------------------------------------------------------------------
// conv1x1 v6: z[b] = W(256x2048) @ x_b(2048x784). M=256 (x once), N-tile 64,
// K-split 4 -> grid (13,4,32)=1664 blocks, 512 thr, 48 KB LDS (3 blocks/CU).
// Wave-specialized staging: waves 0-3 stage A (uint4 from wb/L2), waves 4-7
// gather x as 8 x float4 (128B/thread in flight) into a 128-k B slab.
// ---------------------------------------------------------------------------
__global__ __launch_bounds__(512)
void conv_k(const u16* __restrict__ wb, const float* __restrict__ x,
            float* __restrict__ z0, float* __restrict__ z1,
            float* __restrict__ z2, float* __restrict__ z3)
{
  __shared__ u16 ldsA[256][8][8];    // 32 KB: 256 W rows x 64 k
  __shared__ u16 ldsB[64][16][8];    // 16 KB: 64 n x 128 k
  const int tid = threadIdx.x;
  const int b = blockIdx.z;
  const int n0 = blockIdx.x * 64;
  const int kb0 = blockIdx.y * 512;
  const int wave = tid >> 6, lane = tid & 63;
  const int wm = wave >> 1, wn = wave & 1;    // 4m x 2n
  const int mL = lane & 15, q = lane >> 4;
  const float* xb = x + (long)b * 2048 * 784;
  float* zp = (blockIdx.y == 0) ? z0 : (blockIdx.y == 1) ? z1
            : (blockIdx.y == 2) ? z2 : z3;

  f32x4 acc[4][2];
#pragma unroll
  for (int i = 0; i < 4; ++i)
#pragma unroll
    for (int j = 0; j < 2; ++j) acc[i][j] = {0.f, 0.f, 0.f, 0.f};

  const bool isB = (tid >= 256);
  const int t2 = tid & 255;
  const int o8 = t2 >> 4, nq = t2 & 15;       // B: k-octet 0..15, n-quad 0..15
  const int gnq = n0 + nq * 4;
  const bool nok = (gnq < 784);

  for (int ks = 0; ks < 4; ++ks) {
    const int kg = kb0 + ks * 128;
    __syncthreads();
    if (!isB) {                               // A half 0: k = kg..kg+63
#pragma unroll
      for (int it = 0; it < 8; ++it) {
        const int g = it * 256 + t2;
        const int m = g >> 3, c = g & 7;
        *reinterpret_cast<uint4*>(&ldsA[m][c ^ (m & 7)][0]) =
            *reinterpret_cast<const uint4*>(wb + (long)m * 2048 + kg + c * 8);
      }
    } else {                                  // B: 128-k slab, 8 float4 loads
      float4 f[8];
#pragma unroll
      for (int jk = 0; jk < 8; ++jk)
        f[jk] = nok ? *reinterpret_cast<const float4*>(
                          xb + (long)(kg + o8 * 8 + jk) * 784 + gnq)
                    : make_float4(0.f, 0.f, 0.f, 0.f);
      const float (*ff)[4] = reinterpret_cast<const float(*)[4]>(f);
#pragma unroll
      for (int j = 0; j < 4; ++j) {
        const int n = nq * 4 + j;
        const int ch = o8 ^ (n & 7);
        ushort4 ua, ub;
        ua.x = f2bf(ff[0][j]); ua.y = f2bf(ff[1][j]);
        ua.z = f2bf(ff[2][j]); ua.w = f2bf(ff[3][j]);
        ub.x = f2bf(ff[4][j]); ub.y = f2bf(ff[5][j]);
        ub.z = f2bf(ff[6][j]); ub.w = f2bf(ff[7][j]);
        *reinterpret_cast<ushort4*>(&ldsB[n][ch][0]) = ua;
        *reinterpret_cast<ushort4*>(&ldsB[n][ch][4]) = ub;
      }
    }
    __syncthreads();
    // MFMA half 0 (k-chunks 0..7 of slab)
#pragma unroll
    for (int kk = 0; kk < 2; ++kk) {
      bf16x8 af[4], bfv[2];
#pragma unroll
      for (int i = 0; i < 4; ++i) {
        const int ma = wm * 64 + i * 16 + mL;
        af[i] = *reinterpret_cast<const bf16x8*>(&ldsA[ma][(kk * 4 + q) ^ (ma & 7)][0]);
      }
#pragma unroll
      for (int j = 0; j < 2; ++j) {
        const int nb = wn * 32 + j * 16 + mL;
        bfv[j] = *reinterpret_cast<const bf16x8*>(&ldsB[nb][(kk * 4 + q) ^ (nb & 7)][0]);
      }
#pragma unroll
      for (int i = 0; i < 4; ++i)
#pragma unroll
        for (int j = 0; j < 2; ++j)
          acc[i][j] = __builtin_amdgcn_mfma_f32_16x16x32_bf16(af[i], bfv[j], acc[i][j], 0, 0, 0);
    }
    __syncthreads();
    if (!isB) {                               // A half 1: k = kg+64..kg+127
#pragma unroll
      for (int it = 0; it < 8; ++it) {
        const int g = it * 256 + t2;
        const int m = g >> 3, c = g & 7;
        *reinterpret_cast<uint4*>(&ldsA[m][c ^ (m & 7)][0]) =
            *reinterpret_cast<const uint4*>(wb + (long)m * 2048 + kg + 64 + c * 8);
      }
    }
    __syncthreads();
    // MFMA half 1 (k-chunks 8..15 of slab)
#pragma unroll
    for (int kk = 0; kk < 2; ++kk) {
      bf16x8 af[4], bfv[2];
#pragma unroll
      for (int i = 0; i < 4; ++i) {
        const int ma = wm * 64 + i * 16 + mL;
        af[i] = *reinterpret_cast<const bf16x8*>(&ldsA[ma][(kk * 4 + q) ^ (ma & 7)][0]);
      }
#pragma unroll
      for (int j = 0; j < 2; ++j) {
        const int nb = wn * 32 + j * 16 + mL;
        bfv[j] = *reinterpret_cast<const bf16x8*>(&ldsB[nb][(8 + kk * 4 + q) ^ (nb & 7)][0]);
      }
#pragma unroll
      for (int i = 0; i < 4; ++i)
#pragma unroll
        for (int j = 0; j < 2; ++j)
          acc[i][j] = __builtin_amdgcn_mfma_f32_16x16x32_bf16(af[i], bfv[j], acc[i][j], 0, 0, 0);
    }
  }

#pragma unroll
  for (int i = 0; i < 4; ++i) {
    const int rbase = wm * 64 + i * 16 + q * 4;
#pragma unroll
    for (int j = 0; j < 2; ++j) {
      const int cc = n0 + wn * 32 + j * 16 + mL;
      if (cc >= 784) continue;
#pragma unroll
      for (int rg = 0; rg < 4; ++rg)
        zp[((long)b * 256 + rbase + rg) * 784 + cc] = acc[i][j][rg];
    }
  }
}

// ---------------------------------------------------------------------------
// Gram (512 thr): cov[b] = (1/784) zb@zb^T - mu mu^T; C2 = split(cov).
// ---------------------------------------------------------------------------
__global__ __launch_bounds__(512)
void gram_k(const u16* __restrict__ zb, const float* __restrict__ rs,
            float* __restrict__ cov, u16* __restrict__ C2h, u16* __restrict__ C2l)
{
  __shared__ u16 ldsA[128][8][8];   // 16 KB
  __shared__ u16 ldsB[64][8][8];    // 8 KB
  const int tid = threadIdx.x;
  const int b = blockIdx.z;
  const int col0 = blockIdx.x * 64, row0 = blockIdx.y * 128;
  const int wave = tid >> 6, lane = tid & 63;
  const int wm = wave >> 1, wn = wave & 1;    // 4m x 2n
  const int mL = lane & 15, q = lane >> 4;
  const u16* zbb = zb + (long)b * 256 * 832;

  f32x4 acc[2][2];
#pragma unroll
  for (int i = 0; i < 2; ++i)
#pragma unroll
    for (int j = 0; j < 2; ++j) acc[i][j] = {0.f, 0.f, 0.f, 0.f};

  for (int k0 = 0; k0 < 832; k0 += 64) {
    __syncthreads();
#pragma unroll
    for (int it = 0; it < 2; ++it) {
      const int r = it * 512 + tid;
      const int m = r >> 3, c = r & 7;
      *reinterpret_cast<uint4*>(&ldsA[m][c ^ (m & 7)][0]) =
          *reinterpret_cast<const uint4*>(zbb + (long)(row0 + m) * 832 + k0 + c * 8);
    }
    {
      const int m = tid >> 3, c = tid & 7;
      *reinterpret_cast<uint4*>(&ldsB[m][c ^ (m & 7)][0]) =
          *reinterpret_cast<const uint4*>(zbb + (long)(col0 + m) * 832 + k0 + c * 8);
    }
    __syncthreads();
#pragma unroll
    for (int kk = 0; kk < 2; ++kk) {
      bf16x8 af[2], bfv[2];
#pragma unroll
      for (int i = 0; i < 2; ++i) {
        const int ma = wm * 32 + i * 16 + mL;
        af[i] = *reinterpret_cast<const bf16x8*>(&ldsA[ma][(kk * 4 + q) ^ (ma & 7)][0]);
      }
#pragma unroll
      for (int j = 0; j < 2; ++j) {
        const int nb = wn * 32 + j * 16 + mL;
        bfv[j] = *reinterpret_cast<const bf16x8*>(&ldsB[nb][(kk * 4 + q) ^ (nb & 7)][0]);
      }
#pragma unroll
      for (int i = 0; i < 2; ++i)
#pragma unroll
        for (int j = 0; j < 2; ++j)
          acc[i][j] = __builtin_amdgcn_mfma_f32_16x16x32_bf16(af[i], bfv[j], acc[i][j], 0, 0, 0);
    }
  }
  const float inv_m = 1.f / 784.f;
#pragma unroll
  for (int i = 0; i < 2; ++i) {
    const int rr0 = row0 + wm * 32 + i * 16 + q * 4;
#pragma unroll
    for (int j = 0; j < 2; ++j) {
      const int cc = col0 + wn * 32 + j * 16 + mL;
      const float mu_c = rs[b * 256 + cc] * inv_m;
#pragma unroll
      for (int rg = 0; rg < 4; ++rg) {
        const int rr = rr0 + rg;
        const float mu_r = rs[b * 256 + rr] * inv_m;
        const long o = ((long)b * 256 + rr) * 256 + cc;
        const float cv = fmaf(acc[i][j][rg], inv_m, -mu_r * mu_c);
        cov[o] = cv;
        const u16 h = f2bf(cv);
        C2h[o] = h; C2l[o] = f2bf(cv - bf2f(h));
      }
    }
  }
}

// ---- BN pass 1 (float4): partial sums/sumsq, z = z0+z1+z2+z3 --------------
__global__ __launch_bounds__(256)
void bn_stats_k(const float* __restrict__ z0, const float* __restrict__ z1,
                const float* __restrict__ z2, const float* __restrict__ z3,
                float* __restrict__ ps, float* __restrict__ pq)
{
  const int d = blockIdx.x, sl = blockIdx.y, t = threadIdx.x;
  const int lane = t & 63, wid = t >> 6;
  __shared__ float ws[4], wq[4];
  float s = 0.f, qq = 0.f;
  for (int b = sl * 4; b < sl * 4 + 4; ++b) {
    const long off = ((long)b * 256 + d) * 784;
    for (int q4 = t; q4 < 196; q4 += 256) {
      const float4 a0 = *reinterpret_cast<const float4*>(z0 + off + q4 * 4);
      const float4 a1 = *reinterpret_cast<const float4*>(z1 + off + q4 * 4);
      const float4 a2 = *reinterpret_cast<const float4*>(z2 + off + q4 * 4);
      const float4 a3 = *reinterpret_cast<const float4*>(z3 + off + q4 * 4);
      const float v0 = (a0.x + a1.x) + (a2.x + a3.x);
      const float v1 = (a0.y + a1.y) + (a2.y + a3.y);
      const float v2 = (a0.z + a1.z) + (a2.z + a3.z);
      const float v3 = (a0.w + a1.w) + (a2.w + a3.w);
      s += v0 + v1 + v2 + v3;
      qq = fmaf(v0, v0, fmaf(v1, v1, fmaf(v2, v2, fmaf(v3, v3, qq))));
    }
  }
#pragma unroll
  for (int o = 32; o > 0; o >>= 1) { s += __shfl_down(s, o); qq += __shfl_down(qq, o); }
  if (lane == 0) { ws[wid] = s; wq[wid] = qq; }
  __syncthreads();
  if (t == 0) {
    ps[d * 8 + sl] = ws[0] + ws[1] + ws[2] + ws[3];
    pq[d * 8 + sl] = wq[0] + wq[1] + wq[2] + wq[3];
  }
}

// ---- BN pass 2 (float4): finalize, normalize+ReLU+cast, rowsums -----------
__global__ __launch_bounds__(256)
void bn_apply_k(const float* __restrict__ z0, const float* __restrict__ z1,
                const float* __restrict__ z2, const float* __restrict__ z3,
                const float* __restrict__ gamma, const float* __restrict__ beta,
                const float* __restrict__ ps, const float* __restrict__ pq,
                u16* __restrict__ zb, float* __restrict__ rs)
{
  const int d = blockIdx.x, b = blockIdx.y, t = threadIdx.x;
  const int lane = t & 63, wid = t >> 6;
  __shared__ float bc[2], ws[4];
  if (t == 0) {
    float sum = 0.f, sq = 0.f;
#pragma unroll
    for (int s8 = 0; s8 < 8; ++s8) { sum += ps[d * 8 + s8]; sq += pq[d * 8 + s8]; }
    const float inv_n = 1.f / 25088.f;
    const float mean = sum * inv_n;
    const float var = sq * inv_n - mean * mean;
    const float sc = gamma[d] * rsqrtf(var + 1e-5f);
    bc[0] = sc; bc[1] = fmaf(-mean, sc, beta[d]);
  }
  __syncthreads();
  const float sc = bc[0], sh = bc[1];
  const long off = ((long)b * 256 + d) * 784;
  u16* qp = zb + ((long)b * 256 + d) * 832;
  float rsum = 0.f;
  for (int q4 = t; q4 < 208; q4 += 256) {
    ushort4 u = {0, 0, 0, 0};
    if (q4 < 196) {
      const float4 a0 = *reinterpret_cast<const float4*>(z0 + off + q4 * 4);
      const float4 a1 = *reinterpret_cast<const float4*>(z1 + off + q4 * 4);
      const float4 a2 = *reinterpret_cast<const float4*>(z2 + off + q4 * 4);
      const float4 a3 = *reinterpret_cast<const float4*>(z3 + off + q4 * 4);
      const float v0 = fmaxf(fmaf((a0.x + a1.x) + (a2.x + a3.x), sc, sh), 0.f);
      const float v1 = fmaxf(fmaf((a0.y + a1.y) + (a2.y + a3.y), sc, sh), 0.f);
      const float v2 = fmaxf(fmaf((a0.z + a1.z) + (a2.z + a3.z), sc, sh), 0.f);
      const float v3 = fmaxf(fmaf((a0.w + a1.w) + (a2.w + a3.w), sc, sh), 0.f);
      u.x = f2bf(v0); u.y = f2bf(v1); u.z = f2bf(v2); u.w = f2bf(v3);
      rsum += v0 + v1 + v2 + v3;
    }
    *reinterpret_cast<ushort4*>(qp + q4 * 4) = u;
  }
#pragma unroll
  for (int o = 32; o > 0; o >>= 1) rsum += __shfl_down(rsum, o);
  if (lane == 0) ws[wid] = rsum;
  __syncthreads();
  if (t == 0) rs[b * 256 + d] = ws[0] + ws[1] + ws[2] + ws[3];
}

// ---- power iteration: j-dim split x4 across 1024 threads ------------------
__global__ __launch_bounds__(1024)
void power_k(const float* __restrict__ cov, float* __restrict__ s,
             float* __restrict__ attn2)
{
  const int b = blockIdx.x, tid = threadIdx.x;
  const int i = tid & 255, g = tid >> 8;        // g in 0..3
  const float* A = cov + (long)b * 65536;
  __shared__ float v[256];
  __shared__ float part[4][256];
  __shared__ float red[4];
  if (g == 0) v[i] = 1.f;
  __syncthreads();
  float lam = 1.f;
  for (int it = 0; it < 10; ++it) {
    float u = 0.f;
    const int jb = g * 64;
#pragma unroll 8
    for (int j = jb; j < jb + 64; ++j) u = fmaf(A[(long)j * 256 + i], v[j], u);
    part[g][i] = u;
    __syncthreads();
    if (g == 0) {
      u = part[0][i] + part[1][i] + part[2][i] + part[3][i];
      float ss = u * u;
#pragma unroll
      for (int o = 32; o > 0; o >>= 1) ss += __shfl_down(ss, o);
      if ((i & 63) == 0) red[i >> 6] = ss;
    }
    __syncthreads();
    lam = sqrtf(red[0] + red[1] + red[2] + red[3]);
    if (g == 0) v[i] = u / lam;
    __syncthreads();
  }
  if (tid == 0) { s[b] = 1.8f / lam; attn2[b] = 0.f; }
}

// ---- init: Y0 = split(s*cov); T0 = split(1.5I - 0.5*s*cov)  (Z0 = I) ------
__global__ __launch_bounds__(256)
void init_k(const float* __restrict__ cov, const float* __restrict__ s,
            u16* __restrict__ Yh, u16* __restrict__ Yl,
            u16* __restrict__ Th, u16* __restrict__ Tl)
{
  const int b = blockIdx.y, i = blockIdx.x, j = threadIdx.x;
  const long o = ((long)b * 256 + i) * 256 + j;
  const float a = cov[o] * s[b];
  u16 h = f2bf(a);
  Yh[o] = h; Yl[o] = f2bf(a - bf2f(h));
  float tv = -0.5f * a;
  if (i == j) tv += 1.5f;
  h = f2bf(tv);
  Th[o] = h; Tl[o] = f2bf(tv - bf2f(h));
}

// ---- epilogue: y = (Y/sqrt(s)) * (1 + ||S2||_F/sqrt(s)), triu extract -----
__global__ __launch_bounds__(256)
void out_k(const u16* __restrict__ Yh, const u16* __restrict__ Yl,
           const float* __restrict__ s, const float* __restrict__ attn2,
           float* __restrict__ out)
{
  const int i = blockIdx.x, b = blockIdx.y, j = threadIdx.x;
  if (j < i) return;
  const float inv = rsqrtf(s[b]);
  const float nrm = fmaxf(sqrtf(fmaxf(attn2[b], 0.f)) * inv, 1e-12f);
  const float scv = inv * (1.f + nrm);
  const long o = ((long)b * 256 + i) * 256 + j;
  const long off = (long)b * 32896 + (long)i * 256 - (long)i * (i - 1) / 2 + (j - i);
  out[off] = (bf2f(Yh[o]) + bf2f(Yl[o])) * scv;
}

__global__ __launch_bounds__(256)
void cast_w_k(const float* __restrict__ w, u16* __restrict__ wb)
{
  const int idx = blockIdx.x * 256 + threadIdx.x;
  wb[idx] = f2bf(w[idx]);
}

extern "C" void kernel_launch(void* const* d_in, const int* in_sizes, int n_in,
                              void* d_out, int out_size, void* d_ws, size_t ws_size,
                              hipStream_t stream)
{
  const float* x     = (const float*)d_in[0];   // [32,2048,28,28]
  const float* w     = (const float*)d_in[1];   // [256,2048]
  const float* gamma = (const float*)d_in[2];
  const float* beta  = (const float*)d_in[3];
  float* out = (float*)d_out;

  // ---- workspace: 9 split-pair slots + z0..z3 + zb + cov + st -------------
  const long PS = 4194304;  // u16 per slot (hi 2,097,152 then lo 2,097,152)
  const long LO = 2097152;
  u16* S[9];
  for (int k = 0; k < 9; ++k) S[k] = (u16*)d_ws + (long)k * PS;
  char* base = (char*)d_ws;
  float* z0  = (float*)(base + 75497472);       // 4 x 25,690,112 B
  float* z1  = (float*)(base + 101187584);
  float* z2  = (float*)(base + 126877696);
  float* z3  = (float*)(base + 152567808);
  u16*   zb  = (u16*)(base + 178257920);        // 13,631,488 B
  float* cov = (float*)(base + 191889408);      // 8,388,608 B
  u16*   wbuf = (u16*)(base + 191889408);       // 1 MB, dead before gram
  float* st  = (float*)(base + 200278016);      // ~50 KB of scalars
  float* sv = st, *attn2 = st + 32, *rs = st + 64;
  float* ps = st + 64 + 8192, *pq = ps + 2048;
  u16 *C2 = S[5], *V = S[6], *Ha = S[7], *Hb = S[8];

  const dim3 blk(256), blk5(512);
  const dim3 gF(4, 2, 64);   // fuseN64 launches: 512 blocks x 512 thr
  const dim3 gT(4, 2, 32);   // single-task 128x64: 256 blocks x 512 thr
  const dim3 gE(256, 32);
  const float* nullf = nullptr;

  // 1) conv: W precast, M256/Ksplit4, wave-specialized fat-load staging
  cast_w_k<<<dim3(2048), blk, 0, stream>>>(w, wbuf);
  conv_k<<<dim3(13, 4, 32), blk5, 0, stream>>>(wbuf, x, z0, z1, z2, z3);
  // 2) BN: stats (2048 blocks) + apply (8192 blocks), z = z0+z1+z2+z3
  bn_stats_k<<<dim3(256, 8), blk, 0, stream>>>(z0, z1, z2, z3, ps, pq);
  bn_apply_k<<<dim3(256, 32), blk, 0, stream>>>(z0, z1, z2, z3, gamma, beta, ps, pq, zb, rs);
  // 3) covariance 128x64 tiles (+ C2 split folded)
  gram_k<<<gT, blk5, 0, stream>>>(zb, rs, cov, C2, C2 + LO);
  // 4) lambda_max; s = 1.8/lam; zero attn2
  power_k<<<dim3(32), dim3(1024), 0, stream>>>(cov, sv, attn2);
  // 5) NS init: Y0 -> S0, T0 -> S1 (Z0 = I => Z1 = T0)
  init_k<<<gE, blk, 0, stream>>>(cov, sv, S[0], S[0] + LO, S[1], S[1] + LO);

  // F1: z<32: Y1 = Y0@T0 -> S2 ; z>=32: V = C2@C2 dual-out Ha = H3
  fuseN64_k<1><<<gF, blk5, 0, stream>>>(
      S[0], S[1], S[2], 1.f, 0.f, 0.f, nullf,
      C2, C2, V, Ha, 1.f, 0.f, 0.f,
      1.f / 40320.f, -1.f / 5040.f, 1.f / 720.f, cov, LO);

  // 6) coupled NS iters 1..7, expm H-chain co-scheduled into iters 1..3.
  int iY = 2, iZ = 1, fa = 0, fb = 3, fc = 4;
  for (int it = 1; it <= 7; ++it) {
    const int iT = fa;
    if (it == 1)        // T1 || Hb = H2 = V@Ha - cov/120 + I/24
      fuseN64_k<0><<<gF, blk5, 0, stream>>>(
          S[iZ], S[iY], S[iT], -0.5f, 0.f, 1.5f, nullf,
          V, Ha, Hb, (u16*)nullptr, 1.f, -1.f / 120.f, 1.f / 24.f,
          0.f, 0.f, 0.f, cov, LO);
    else if (it == 2)   // T2 || Ha = H1 = V@Hb - cov/6 + I/2
      fuseN64_k<0><<<gF, blk5, 0, stream>>>(
          S[iZ], S[iY], S[iT], -0.5f, 0.f, 1.5f, nullf,
          V, Hb, Ha, (u16*)nullptr, 1.f, -1.f / 6.f, 0.5f,
          0.f, 0.f, 0.f, cov, LO);
    else if (it == 3)   // T3 || Hb = H0 = V@Ha - cov + I = e^{-cov}
      fuseN64_k<0><<<gF, blk5, 0, stream>>>(
          S[iZ], S[iY], S[iT], -0.5f, 0.f, 1.5f, nullf,
          V, Ha, Hb, (u16*)nullptr, 1.f, -1.f, 1.f,
          0.f, 0.f, 0.f, cov, LO);
    else                // T4..T7 standalone
      gemmN64_k<0><<<gT, blk5, 0, stream>>>(
          S[iZ], S[iZ] + LO, S[iY], S[iY] + LO, S[iT], S[iT] + LO,
          nullf, -0.5f, 0.f, 1.5f, (float*)nullptr);
    if (it < 7) {       // pair: Y' = Y@T ; Z' = T@Z  (both plain)
      fuseN64_k<0><<<gF, blk5, 0, stream>>>(
          S[iY], S[iT], S[fb], 1.f, 0.f, 0.f, nullf,
          S[iT], S[iZ], S[fc], (u16*)nullptr, 1.f, 0.f, 0.f,
          0.f, 0.f, 0.f, nullf, LO);
      const int nY = fb, nZ = fc;
      fa = iY; fb = iZ; fc = iT;
      iY = nY; iZ = nZ;
    } else {            // last iter: Z not needed
      gemmN64_k<0><<<gT, blk5, 0, stream>>>(
          S[iY], S[iY] + LO, S[iT], S[iT] + LO, S[fb], S[fb] + LO,
          nullf, 1.f, 0.f, 0.f, (float*)nullptr);
      iY = fb;
    }
  }

  // 7) ||Y@E||_F^2 -> attn2 (atomic, no C write); epilogue
  gemmN64_k<2><<<gT, blk5, 0, stream>>>(
      S[iY], S[iY] + LO, Hb, Hb + LO, (u16*)nullptr, (u16*)nullptr,
      nullf, 1.f, 0.f, 0.f, attn2);
  out_k<<<gE, blk, 0, stream>>>(S[iY], S[iY] + LO, sv, attn2, out);
}